// Round 4
// baseline (664.757 us; speedup 1.0000x reference)
//
#include <hip/hip_runtime.h>
#include <math.h>

#define B_  32
#define S_  2048
#define DV  1024
#define U_  1024

typedef __attribute__((ext_vector_type(8))) short bf16x8;
typedef __attribute__((ext_vector_type(4))) float f32x4;

__device__ __forceinline__ unsigned short f2bf(float f) {
    unsigned int x = __float_as_uint(f);
    return (unsigned short)((x + 0x7fffu + ((x >> 16) & 1u)) >> 16);
}

__device__ __forceinline__ float tanh_fast(float x) {
    float ax = fabsf(x);
    float e  = __expf(ax + ax);
    float t  = 1.0f - __fdividef(2.0f, e + 1.0f);
    return copysignf(t, x);
}

// async global->LDS, 16 B per lane. Dest collapses to wave-uniform base + lane*16.
__device__ __forceinline__ void gld16(void* lds, const void* g) {
    __builtin_amdgcn_global_load_lds((const __attribute__((address_space(1))) unsigned int*)g,
                                     (__attribute__((address_space(3))) unsigned int*)lds,
                                     16, 0, 0);
}

// ================= fused prep: cvt(values->bf16) + W1T + projq ==============
// blocks [0,256): W1 [k][u] -> W1T [u][k] bf16 (64x64 tiles)
// blocks [256,288): t[b,u] = b1[u]+b2[u]+query[b,:]@W2[:,u]  (one block per b)
// blocks [288,33056): values fp32 -> bf16, 8 elems/thread
__launch_bounds__(256)
__global__ void pre_kernel(const float* __restrict__ values, unsigned short* __restrict__ Abf,
                           const float* __restrict__ W1, unsigned short* __restrict__ W1T,
                           const float* __restrict__ q, const float* __restrict__ W2,
                           const float* __restrict__ b1, const float* __restrict__ b2,
                           float* __restrict__ t) {
    __shared__ float shbuf[64 * 65];
    const int blk = blockIdx.x;
    const int tid = threadIdx.x;

    if (blk >= 288) {
        size_t i = ((size_t)(blk - 288) * 256 + tid) * 8;
        float4 f0 = *(const float4*)(values + i);
        float4 f1 = *(const float4*)(values + i + 4);
        union { unsigned short s[8]; uint4 u; } p;
        p.s[0] = f2bf(f0.x); p.s[1] = f2bf(f0.y); p.s[2] = f2bf(f0.z); p.s[3] = f2bf(f0.w);
        p.s[4] = f2bf(f1.x); p.s[5] = f2bf(f1.y); p.s[6] = f2bf(f1.z); p.s[7] = f2bf(f1.w);
        *(uint4*)(Abf + i) = p.u;
    } else if (blk < 256) {
        // W1T role
        const int k0 = (blk & 15) * 64, u0 = (blk >> 4) * 64;
        const int lr = tid >> 4, lc = (tid & 15) * 4;
#pragma unroll
        for (int i = 0; i < 4; ++i) {
            float4 f = *(const float4*)&W1[(size_t)(k0 + lr + i * 16) * U_ + u0 + lc];
            shbuf[(lr + i * 16) * 65 + lc + 0] = f.x;
            shbuf[(lr + i * 16) * 65 + lc + 1] = f.y;
            shbuf[(lr + i * 16) * 65 + lc + 2] = f.z;
            shbuf[(lr + i * 16) * 65 + lc + 3] = f.w;
        }
        __syncthreads();
        const int ur = tid >> 2, kq = (tid & 3) * 16;
        union { unsigned short s[8]; uint4 u; } p0, p1;
#pragma unroll
        for (int e = 0; e < 8; ++e) p0.s[e] = f2bf(shbuf[(kq + e) * 65 + ur]);
#pragma unroll
        for (int e = 0; e < 8; ++e) p1.s[e] = f2bf(shbuf[(kq + 8 + e) * 65 + ur]);
        unsigned short* dst = W1T + (size_t)(u0 + ur) * 1024 + k0 + kq;
        *(uint4*)dst       = p0.u;
        *(uint4*)(dst + 8) = p1.u;
    } else {
        // projq role
        const int b = blk - 256;
#pragma unroll
        for (int i = 0; i < 4; ++i) shbuf[tid + i * 256] = q[b * DV + tid + i * 256];
        __syncthreads();
        float a0 = 0.f, a1 = 0.f, a2 = 0.f, a3 = 0.f;
#pragma unroll 8
        for (int d = 0; d < 1024; ++d) {
            float qd = shbuf[d];
            const float* wr = W2 + (size_t)d * U_ + tid;
            a0 += qd * wr[0];
            a1 += qd * wr[256];
            a2 += qd * wr[512];
            a3 += qd * wr[768];
        }
        t[b * U_ + tid      ] = a0 + b1[tid      ] + b2[tid      ];
        t[b * U_ + tid + 256] = a1 + b1[tid + 256] + b2[tid + 256];
        t[b * U_ + tid + 512] = a2 + b1[tid + 512] + b2[tid + 512];
        t[b * U_ + tid + 768] = a3 + b1[tid + 768] + b2[tid + 768];
    }
}

// ================= scores: MFMA GEMM + fused tanh/V epilogue ================
// Block 128(s) x 256(u), 4 waves 2x2, wave 64x128. KT=32.
// LDS: unpadded row stride 32 shorts; 16B chunk c of row r stored at slot c^((r>>1)&3)
// -> global_load_lds lane-contiguous AND ds_read_b128 frag reads <=2-way (free).
// Each u-tile writes its own score slab (no global atomics, no zero-init).
__launch_bounds__(256, 2)
__global__ void scores_mfma(const unsigned short* __restrict__ Abf,
                            const unsigned short* __restrict__ W1T,
                            const float* __restrict__ t,
                            const float* __restrict__ V,
                            float* __restrict__ scores4) {
    __shared__ __align__(16) unsigned short sAB[(128 + 256) * 32];
    __shared__ float fscore[128];

    const int tid  = threadIdx.x;
    const int lane = tid & 63;
    const int wv   = tid >> 6;
    const int wm = wv & 1, wn = wv >> 1;
    const int l15 = lane & 15, lq = lane >> 4;

    // XCD swizzle: the 4 u-tile blocks sharing an A-strip land on one XCD
    const int id    = blockIdx.x;
    const int utile = (id >> 3) & 3;
    const int stile = (id & 7) | ((id >> 5) << 3);
    const int row0  = stile * 128;          // global s-row (b*2048 + s_local)
    const int b     = row0 >> 11;
    const int u0    = utile * 256;

    if (tid < 128) fscore[tid] = 0.f;

    // ---- staging descriptors: 6 x 16B async loads per thread per k-step
    const int srow = lane >> 2;    // row within 16-row window
    const int sc   = lane & 3;     // LDS slot chunk
    const int arow0 = wv * 32 + srow;
    const int arow1 = arow0 + 16;
    unsigned short* ldsA0 = &sAB[arow0 * 32 + sc * 8];
    unsigned short* ldsA1 = &sAB[arow1 * 32 + sc * 8];
    const unsigned short* gA0 = Abf + (size_t)(row0 + arow0) * 1024 + (sc ^ ((arow0 >> 1) & 3)) * 8;
    const unsigned short* gA1 = Abf + (size_t)(row0 + arow1) * 1024 + (sc ^ ((arow1 >> 1) & 3)) * 8;
    unsigned short* ldsB_[4];
    const unsigned short* gB_[4];
#pragma unroll
    for (int i = 0; i < 4; ++i) {
        int br = wv * 64 + 16 * i + srow;
        ldsB_[i] = &sAB[(128 + br) * 32 + sc * 8];
        gB_[i]   = W1T + (size_t)(u0 + br) * 1024 + (sc ^ ((br >> 1) & 3)) * 8;
    }

    // ---- fragment read offsets (swizzle-aware), in shorts
    int aoff[4], boff[8];
#pragma unroll
    for (int i = 0; i < 4; ++i) {
        int r = 64 * wm + 16 * i + l15;
        aoff[i] = r * 32 + (lq ^ ((r >> 1) & 3)) * 8;
    }
#pragma unroll
    for (int j = 0; j < 8; ++j) {
        int r = 128 * wn + 16 * j + l15;
        boff[j] = (128 + r) * 32 + (lq ^ ((r >> 1) & 3)) * 8;
    }

    f32x4 acc[4][8];
#pragma unroll
    for (int i = 0; i < 4; ++i)
#pragma unroll
        for (int j = 0; j < 8; ++j) acc[i][j] = (f32x4)0.f;

    for (int ks = 0; ks < 32; ++ks) {
        __syncthreads();
        gld16(ldsA0, gA0);
        gld16(ldsA1, gA1);
        gld16(ldsB_[0], gB_[0]);
        gld16(ldsB_[1], gB_[1]);
        gld16(ldsB_[2], gB_[2]);
        gld16(ldsB_[3], gB_[3]);
        gA0 += 32; gA1 += 32;
        gB_[0] += 32; gB_[1] += 32; gB_[2] += 32; gB_[3] += 32;
        __syncthreads();

        bf16x8 af[4];
#pragma unroll
        for (int i = 0; i < 4; ++i) af[i] = *(const bf16x8*)&sAB[aoff[i]];
#pragma unroll
        for (int j = 0; j < 8; ++j) {
            bf16x8 bfj = *(const bf16x8*)&sAB[boff[j]];
#pragma unroll
            for (int i = 0; i < 4; ++i)
                acc[i][j] = __builtin_amdgcn_mfma_f32_16x16x32_bf16(af[i], bfj, acc[i][j], 0, 0, 0);
        }
    }

    // epilogue: fscore[m] += sum_u tanh(P + t[b,u]) * V[u]
    float tu[8], vu[8];
#pragma unroll
    for (int j = 0; j < 8; ++j) {
        int u = u0 + 128 * wn + 16 * j + l15;
        tu[j] = t[b * U_ + u];
        vu[j] = V[u];
    }
#pragma unroll
    for (int i = 0; i < 4; ++i) {
#pragma unroll
        for (int r = 0; r < 4; ++r) {
            float p = 0.f;
#pragma unroll
            for (int j = 0; j < 8; ++j) p += tanh_fast(acc[i][j][r] + tu[j]) * vu[j];
            p += __shfl_xor(p, 1);
            p += __shfl_xor(p, 2);
            p += __shfl_xor(p, 4);
            p += __shfl_xor(p, 8);
            if (l15 == 0) atomicAdd(&fscore[64 * wm + 16 * i + lq * 4 + r], p);
        }
    }
    __syncthreads();
    if (tid < 128) scores4[(size_t)utile * (B_ * S_) + row0 + tid] = fscore[tid];
}

// ================= softmax over S (sums 4 slabs) + ctx zero =================
__global__ void softmax4_kernel(const float* __restrict__ s4, float* __restrict__ wout,
                                float* __restrict__ ctx) {
    int b = blockIdx.x;
    int tid = threadIdx.x;
#pragma unroll
    for (int i = 0; i < 4; ++i) ctx[b * DV + tid + i * 256] = 0.f;
    __shared__ float red[256];
    float v[8];
    float m = -1e30f;
#pragma unroll
    for (int i = 0; i < 8; ++i) {
        size_t idx = (size_t)b * S_ + tid + i * 256;
        v[i] = s4[idx] + s4[idx + 65536] + s4[idx + 131072] + s4[idx + 196608];
        m = fmaxf(m, v[i]);
    }
    red[tid] = m; __syncthreads();
    for (int off = 128; off > 0; off >>= 1) {
        if (tid < off) red[tid] = fmaxf(red[tid], red[tid + off]);
        __syncthreads();
    }
    m = red[0];
    __syncthreads();
    float s = 0.f;
#pragma unroll
    for (int i = 0; i < 8; ++i) { v[i] = __expf(v[i] - m); s += v[i]; }
    red[tid] = s; __syncthreads();
    for (int off = 128; off > 0; off >>= 1) {
        if (tid < off) red[tid] += red[tid + off];
        __syncthreads();
    }
    float inv = 1.f / red[0];
#pragma unroll
    for (int i = 0; i < 8; ++i) wout[(size_t)b * S_ + tid + i * 256] = v[i] * inv;
}

// ================= context: float4 weighted sum =============================
__global__ void context4_kernel(const float* __restrict__ values, const float* __restrict__ w,
                                float* __restrict__ ctx) {
    int b  = blockIdx.x;
    int sc = blockIdx.y;
    int tid = threadIdx.x;
    __shared__ float ws_[256];
    ws_[tid] = w[(size_t)b * S_ + sc * 256 + tid];
    __syncthreads();
    float4 acc = {0.f, 0.f, 0.f, 0.f};
    const float* vp = values + ((size_t)b * S_ + sc * 256) * (size_t)DV + tid * 4;
#pragma unroll 4
    for (int s = 0; s < 256; ++s) {
        float4 vv = *(const float4*)(vp + (size_t)s * DV);
        float wv = ws_[s];
        acc.x += wv * vv.x; acc.y += wv * vv.y; acc.z += wv * vv.z; acc.w += wv * vv.w;
    }
    atomicAdd(&ctx[b * DV + tid * 4 + 0], acc.x);
    atomicAdd(&ctx[b * DV + tid * 4 + 1], acc.y);
    atomicAdd(&ctx[b * DV + tid * 4 + 2], acc.z);
    atomicAdd(&ctx[b * DV + tid * 4 + 3], acc.w);
}

// ================= fallback fp32 path (proven R1 kernels) ===================
__global__ void init_kernel(const float* __restrict__ b1, const float* __restrict__ b2,
                            float* __restrict__ t, float* __restrict__ ctx) {
    int i = blockIdx.x * 256 + threadIdx.x;
    int u = i & (U_ - 1);
    t[i]   = b1[u] + b2[u];
    ctx[i] = 0.f;
}

__global__ void projq_kernel(const float* __restrict__ q, const float* __restrict__ W2,
                             float* __restrict__ t) {
    int b  = blockIdx.x;
    int ks = blockIdx.y;
    int tid = threadIdx.x;
    __shared__ float qs[256];
    qs[tid] = q[b * DV + ks * 256 + tid];
    __syncthreads();
    float a0 = 0.f, a1 = 0.f, a2 = 0.f, a3 = 0.f;
    const float* w = W2 + (size_t)(ks * 256) * U_;
    for (int d = 0; d < 256; ++d) {
        float qd = qs[d];
        const float* wr = w + (size_t)d * U_ + tid;
        a0 += qd * wr[0];
        a1 += qd * wr[256];
        a2 += qd * wr[512];
        a3 += qd * wr[768];
    }
    atomicAdd(&t[b * U_ + tid      ], a0);
    atomicAdd(&t[b * U_ + tid + 256], a1);
    atomicAdd(&t[b * U_ + tid + 512], a2);
    atomicAdd(&t[b * U_ + tid + 768], a3);
}

__launch_bounds__(256, 2)
__global__ void scores_vec(const float* __restrict__ values, const float* __restrict__ W1,
                           const float* __restrict__ t, const float* __restrict__ V,
                           float* __restrict__ scores) {
    __shared__ float vA[16][132];
    __shared__ float vB[16][68];
    __shared__ float fscore[128];
    const int b   = blockIdx.y;
    const int s0  = blockIdx.x * 128;
    const int tid = threadIdx.x;
    const int tx  = tid & 15, ty = tid >> 4;
    if (tid < 128) fscore[tid] = 0.f;
    const float* vbase = values + ((size_t)b * S_ + s0) * (size_t)DV;
    const int lm = tid >> 2, lkq = (tid & 3) * 4;
    const int lbk = tid >> 4, lbj = (tid & 15) * 4;
    for (int nt = 0; nt < U_ / 64; ++nt) {
        const int u0 = nt * 64;
        float acc[8][4];
#pragma unroll
        for (int i = 0; i < 8; ++i)
#pragma unroll
            for (int j = 0; j < 4; ++j) acc[i][j] = 0.f;
        for (int k0 = 0; k0 < DV; k0 += 16) {
            __syncthreads();
            const float4 v0 = *(const float4*)(vbase + (size_t)lm * DV + k0 + lkq);
            const float4 v1 = *(const float4*)(vbase + (size_t)(lm + 64) * DV + k0 + lkq);
            vA[lkq + 0][lm] = v0.x; vA[lkq + 1][lm] = v0.y;
            vA[lkq + 2][lm] = v0.z; vA[lkq + 3][lm] = v0.w;
            vA[lkq + 0][lm + 64] = v1.x; vA[lkq + 1][lm + 64] = v1.y;
            vA[lkq + 2][lm + 64] = v1.z; vA[lkq + 3][lm + 64] = v1.w;
            *(float4*)&vB[lbk][lbj] = *(const float4*)(W1 + (size_t)(k0 + lbk) * U_ + u0 + lbj);
            __syncthreads();
#pragma unroll
            for (int k = 0; k < 16; ++k) {
                float4 va0 = *(const float4*)&vA[k][ty * 8];
                float4 va1 = *(const float4*)&vA[k][ty * 8 + 4];
                float4 vb  = *(const float4*)&vB[k][tx * 4];
                float a_[8] = {va0.x, va0.y, va0.z, va0.w, va1.x, va1.y, va1.z, va1.w};
                float b_[4] = {vb.x, vb.y, vb.z, vb.w};
#pragma unroll
                for (int i = 0; i < 8; ++i)
#pragma unroll
                    for (int j = 0; j < 4; ++j) acc[i][j] += a_[i] * b_[j];
            }
        }
        float tq[4], vv[4];
#pragma unroll
        for (int j = 0; j < 4; ++j) {
            int u = u0 + tx * 4 + j;
            tq[j] = t[b * U_ + u];
            vv[j] = V[u];
        }
#pragma unroll
        for (int i = 0; i < 8; ++i) {
            float p = 0.f;
#pragma unroll
            for (int j = 0; j < 4; ++j) p += tanhf(acc[i][j] + tq[j]) * vv[j];
            p += __shfl_down(p, 8, 16);
            p += __shfl_down(p, 4, 16);
            p += __shfl_down(p, 2, 16);
            p += __shfl_down(p, 1, 16);
            if (tx == 0) fscore[ty * 8 + i] += p;
        }
    }
    __syncthreads();
    if (tid < 128) scores[(size_t)b * S_ + s0 + tid] = fscore[tid];
}

__global__ void softmax_kernel(const float* __restrict__ scores, float* __restrict__ wout) {
    int b = blockIdx.x;
    int tid = threadIdx.x;
    __shared__ float red[256];
    float v[8];
    float m = -1e30f;
#pragma unroll
    for (int i = 0; i < 8; ++i) {
        v[i] = scores[(size_t)b * S_ + tid + i * 256];
        m = fmaxf(m, v[i]);
    }
    red[tid] = m; __syncthreads();
    for (int off = 128; off > 0; off >>= 1) {
        if (tid < off) red[tid] = fmaxf(red[tid], red[tid + off]);
        __syncthreads();
    }
    m = red[0];
    __syncthreads();
    float s = 0.f;
#pragma unroll
    for (int i = 0; i < 8; ++i) { v[i] = __expf(v[i] - m); s += v[i]; }
    red[tid] = s; __syncthreads();
    for (int off = 128; off > 0; off >>= 1) {
        if (tid < off) red[tid] += red[tid + off];
        __syncthreads();
    }
    float inv = 1.f / red[0];
#pragma unroll
    for (int i = 0; i < 8; ++i) wout[(size_t)b * S_ + tid + i * 256] = v[i] * inv;
}

// ================= launch ===================================================
extern "C" void kernel_launch(void* const* d_in, const int* in_sizes, int n_in,
                              void* d_out, int out_size, void* d_ws, size_t ws_size,
                              hipStream_t stream) {
    const float* query  = (const float*)d_in[0];
    const float* values = (const float*)d_in[1];
    const float* W1     = (const float*)d_in[2];
    const float* b1     = (const float*)d_in[3];
    const float* W2     = (const float*)d_in[4];
    const float* b2     = (const float*)d_in[5];
    const float* V      = (const float*)d_in[6];
    // bV (d_in[7]): uniform score shift, softmax-invariant.

    float* out  = (float*)d_out;
    float* ctx  = out;                 // [32, 1024]
    float* wout = out + B_ * DV;       // [32, 2048]

    char* ws = (char*)d_ws;
    const size_t W1T_BYTES = (size_t)U_ * DV * 2;        // 2 MB
    const size_t T_BYTES   = (size_t)B_ * U_ * 4;        // 128 KB
    const size_t S4_BYTES  = (size_t)4 * B_ * S_ * 4;    // 1 MB
    const size_t ABF_BYTES = (size_t)B_ * S_ * DV * 2;   // 128 MB

    if (ws_size >= W1T_BYTES + T_BYTES + S4_BYTES + ABF_BYTES) {
        unsigned short* W1T = (unsigned short*)ws;
        float* t       = (float*)(ws + W1T_BYTES);
        float* scores4 = (float*)(ws + W1T_BYTES + T_BYTES);
        unsigned short* Abf = (unsigned short*)(ws + W1T_BYTES + T_BYTES + S4_BYTES);

        pre_kernel     <<<dim3(33056),  256, 0, stream>>>(values, Abf, W1, W1T, query, W2, b1, b2, t);
        scores_mfma    <<<dim3(2048),   256, 0, stream>>>(Abf, W1T, t, V, scores4);
        softmax4_kernel<<<dim3(32),     256, 0, stream>>>(scores4, wout, ctx);
        context4_kernel<<<dim3(32, 8),  256, 0, stream>>>(values, wout, ctx);
    } else {
        // fp32 vector fallback (384 KB ws)
        float* t      = (float*)ws;
        float* scores = t + B_ * U_;

        init_kernel   <<<dim3(128),      256, 0, stream>>>(b1, b2, t, ctx);
        projq_kernel  <<<dim3(32, 4),    256, 0, stream>>>(query, W2, t);
        scores_vec    <<<dim3(16, 32),   256, 0, stream>>>(values, W1, t, V, scores);
        softmax_kernel<<<dim3(32),       256, 0, stream>>>(scores, wout);
        context4_kernel<<<dim3(32, 8),   256, 0, stream>>>(values, wout, ctx);  // ctx zeroed by init
    }
}